// Round 1
// baseline (1131.334 us; speedup 1.0000x reference)
//
#include <hip/hip_runtime.h>

// Problem constants
#define BB 64
#define LL 256
#define DV 512
#define DT 41
#define NT 32
#define MM 32
#define VV 64
#define KK 8
#define D2 1106          // 2*(DV+DT)
#define D2P 1120         // padded to 35*32
#define FIVE_DV 2560

// Output flat offsets (floats)
#define OFF_NEWH 0ULL
#define OFF_C    9060352ULL
#define OFF_NEWD 17448960ULL
#define OFF_LOSS 51003392ULL
#define OFF_DT   51003393ULL

typedef __bf16 bf16x8 __attribute__((ext_vector_type(8)));
typedef float f32x4 __attribute__((ext_vector_type(4)));
typedef unsigned short u16x8 __attribute__((ext_vector_type(8)));

__device__ __forceinline__ unsigned short f2bf(float f) {
    unsigned u = __float_as_uint(f);
    u = (u + 0x7fffu + ((u >> 16) & 1u)) >> 16;
    return (unsigned short)u;
}
__device__ __forceinline__ float bf2f(unsigned short h) {
    return __uint_as_float(((unsigned)h) << 16);
}
__device__ __forceinline__ float sigm(float x) {
    return 1.0f / (1.0f + __expf(-x));
}
__device__ __forceinline__ float tanh_f(float x) {
    // tanh(x) = 1 - 2/(exp(2x)+1); saturates correctly at +-inf
    return 1.0f - 2.0f / (__expf(2.0f * x) + 1.0f);
}

// ---------------------------------------------------------------------------
// Kernel: build padded bf16 hlr = concat(hl, hr) with zero K-pad
// grid 16384 blocks x 256
__global__ __launch_bounds__(256) void k_hlr(const float* __restrict__ hl,
                                             const float* __restrict__ hr,
                                             unsigned short* __restrict__ hlr) {
    int row = blockIdx.x;
    int t = threadIdx.x;
    size_t sbase = (size_t)row * 553;
    size_t obase = (size_t)row * D2P;
    for (int q = 0; q < 5; ++q) {
        int k = t + q * 256;
        if (k < D2P) {
            float v = 0.0f;
            if (k < 553) v = hl[sbase + k];
            else if (k < D2) v = hr[sbase + (k - 553)];
            hlr[obase + k] = f2bf(v);
        }
    }
}

// ---------------------------------------------------------------------------
// Kernel: per-batch decoder template logits (exact fp32) + argmax codes
// grid 64 blocks x 64
__global__ __launch_bounds__(64) void k_dec(const float* __restrict__ type_emb,
                                            const float* __restrict__ dec_W,
                                            const float* __restrict__ dec_b,
                                            const int* __restrict__ tts,
                                            int* __restrict__ codes,
                                            float* __restrict__ dtf) {
    int b = blockIdx.x;
    int t = threadIdx.x;
    int tt = tts[b];
    int e = tt - 9;
    __shared__ float dv[24];
    if (t < 24) {
        float v;
        if (tt == 25) {
            int k = t / 3, c = t % 3;
            int code = (k == 0) ? 0 : 2;
            v = (c == code) ? 1.0f : 0.0f;
        } else {
            float s = dec_b[e * 24 + t];
            const float* em = type_emb + (size_t)tt * DV;
            const float* w = dec_W + (size_t)e * DV * 24 + t;
            for (int d = 0; d < DV; ++d) s += em[d] * w[(size_t)d * 24];
            v = s;
        }
        dv[t] = v;
        dtf[b * 24 + t] = v;
    }
    __syncthreads();
    if (t < 8) {
        float b0 = dv[t * 3], b1 = dv[t * 3 + 1], b2 = dv[t * 3 + 2];
        int code = 0;
        float best = b0;
        if (b1 > best) { best = b1; code = 1; }
        if (b2 > best) { best = b2; code = 2; }
        codes[b * 8 + t] = code;
    }
}

// ---------------------------------------------------------------------------
// Kernel: grouped GEMM v = hlr @ comp_W[t] + comp_b[t], output bf16 to vws
// tile 128(L) x 128(N), 256 threads (4 waves 2x2), bf16 MFMA 16x16x32
// grid (20, 2, 64)
__global__ __launch_bounds__(256, 2) void k_gemm(const unsigned short* __restrict__ hlr,
                                                 const float* __restrict__ W,
                                                 const float* __restrict__ bias,
                                                 const int* __restrict__ tts,
                                                 unsigned short* __restrict__ vws) {
    __shared__ __align__(16) unsigned short As[128 * 32];
    __shared__ __align__(16) unsigned short Bs[128 * 32];

    int b = blockIdx.z;
    int l0 = blockIdx.y * 128;
    int n0 = blockIdx.x * 128;
    int e = tts[b] - 9;
    const float* Wb = W + (size_t)e * D2 * FIVE_DV;

    int tid = threadIdx.x;
    int lane = tid & 63;
    int w = tid >> 6;
    int wr = w >> 1, wc = w & 1;
    int q = lane >> 4;
    int mr = lane & 15;

    int nB = tid & 127;   // staging column
    int kg2 = tid >> 7;   // staging k-group half

    const unsigned short* Arow = hlr + (size_t)(b * LL + l0) * D2P;

    f32x4 acc[4][4];
#pragma unroll
    for (int i = 0; i < 4; ++i)
#pragma unroll
        for (int j = 0; j < 4; ++j) acc[i][j] = (f32x4)0.0f;

    for (int ks = 0; ks < 35; ++ks) {
        int k0 = ks * 32;
        __syncthreads();
        // ---- stage A (bf16, already padded): 128x32, contiguous 16B chunks
#pragma unroll
        for (int i = 0; i < 2; ++i) {
            int idx = i * 256 + tid;
            int row = idx >> 2;
            int ko = (idx & 3) * 8;
            u16x8 av = *(const u16x8*)(Arow + (size_t)row * D2P + k0 + ko);
            *(u16x8*)&As[idx * 8] = av;
        }
        // ---- stage B (fp32 -> bf16, transposed to [n][k], XOR-swizzled)
#pragma unroll
        for (int it = 0; it < 2; ++it) {
            int kg = kg2 * 2 + it;
            int kb = kg * 8;
            u16x8 bv;
#pragma unroll
            for (int j = 0; j < 8; ++j) {
                int kk = k0 + kb + j;
                float f = (kk < D2) ? Wb[(size_t)kk * FIVE_DV + n0 + nB] : 0.0f;
                bv[j] = f2bf(f);
            }
            *(u16x8*)&Bs[nB * 32 + ((kg ^ (nB & 3)) << 3)] = bv;
        }
        __syncthreads();
        // ---- fragments + MFMA
        bf16x8 af[4], bfr[4];
#pragma unroll
        for (int mt = 0; mt < 4; ++mt)
            af[mt] = *(const bf16x8*)&As[(wr * 64 + mt * 16 + mr) * 32 + q * 8];
#pragma unroll
        for (int nt = 0; nt < 4; ++nt) {
            int nn = wc * 64 + nt * 16 + mr;
            bfr[nt] = *(const bf16x8*)&Bs[nn * 32 + ((q ^ (nn & 3)) << 3)];
        }
#pragma unroll
        for (int mt = 0; mt < 4; ++mt)
#pragma unroll
            for (int nt = 0; nt < 4; ++nt)
                acc[mt][nt] = __builtin_amdgcn_mfma_f32_16x16x32_bf16(
                    af[mt], bfr[nt], acc[mt][nt], 0, 0, 0);
    }

    // ---- epilogue: add bias, write bf16 v
#pragma unroll
    for (int nt = 0; nt < 4; ++nt) {
        int col = n0 + wc * 64 + nt * 16 + mr;
        float bv = bias[(size_t)e * FIVE_DV + col];
#pragma unroll
        for (int mt = 0; mt < 4; ++mt) {
            int rowg = l0 + wr * 64 + mt * 16 + q * 4;
            size_t base = ((size_t)(b * LL) + rowg) * FIVE_DV + col;
#pragma unroll
            for (int r = 0; r < 4; ++r)
                vws[base + (size_t)r * FIVE_DV] = f2bf(acc[mt][nt][r] + bv);
        }
    }
}

// ---------------------------------------------------------------------------
// Kernel: LSTM gating + type-predictor MLP + gumbel softmax, writes c & new_h
// grid 16384 x 256
__global__ __launch_bounds__(256) void k_cell(const unsigned short* __restrict__ vws,
                                              const float* __restrict__ cl,
                                              const float* __restrict__ cr,
                                              const float* __restrict__ W1,
                                              const float* __restrict__ b1,
                                              const float* __restrict__ W2,
                                              const float* __restrict__ b2,
                                              const float* __restrict__ W3,
                                              const float* __restrict__ b3,
                                              const float* __restrict__ gumbel,
                                              float* __restrict__ out) {
    int row = blockIdx.x;
    int t = threadIdx.x;
    __shared__ float hv[512];
    __shared__ float red[256];
    __shared__ float h1[32], h2[32], zz[41];

    const unsigned short* v = vws + (size_t)row * FIVE_DV;
    size_t c_off = OFF_C + (size_t)row * DV;
    size_t h_off = (size_t)row * 553;
    size_t cc = (size_t)row * DV;

#pragma unroll
    for (int i = 0; i < 2; ++i) {
        int j = t + i * 256;
        float ig = bf2f(v[j]);
        float fl = bf2f(v[512 + j]);
        float fr = bf2f(v[1024 + j]);
        float uu = bf2f(v[1536 + j]);
        float oo = bf2f(v[2048 + j]);
        float cv = cl[cc + j] * sigm(fl + 1.0f) + cr[cc + j] * sigm(fr + 1.0f)
                 + tanh_f(uu) * sigm(ig);
        float h = sigm(oo) * tanh_f(cv);
        out[c_off + j] = cv;
        out[h_off + j] = h;
        hv[j] = h;
    }
    __syncthreads();
    // h1 = relu(hv @ W1 + b1): 32 outputs, 8 partial groups
    {
        int jj = t & 31, g = t >> 5;
        float p = 0.0f;
        int d0 = g * 64;
        for (int d = d0; d < d0 + 64; ++d) p += hv[d] * W1[d * 32 + jj];
        red[t] = p;
    }
    __syncthreads();
    if (t < 32) {
        float s = b1[t];
#pragma unroll
        for (int g = 0; g < 8; ++g) s += red[g * 32 + t];
        h1[t] = s > 0.0f ? s : 0.0f;
    }
    __syncthreads();
    if (t < 32) {
        float s = b2[t];
        for (int d = 0; d < 32; ++d) s += h1[d] * W2[d * 32 + t];
        h2[t] = s > 0.0f ? s : 0.0f;
    }
    __syncthreads();
    if (t < 41) {
        float s = b3[t];
        for (int d = 0; d < 32; ++d) s += h2[d] * W3[d * 41 + t];
        zz[t] = s + gumbel[(size_t)row * DT + t];
    }
    __syncthreads();
    if (t < 64) {
        float val = (t < 41) ? zz[t] : -3.4e38f;
        float m = val;
        for (int off = 32; off; off >>= 1) m = fmaxf(m, __shfl_xor(m, off, 64));
        float ex = (t < 41) ? __expf(val - m) : 0.0f;
        float s = ex;
        for (int off = 32; off; off >>= 1) s += __shfl_xor(s, off, 64);
        if (t < 41) out[h_off + 512 + t] = ex / s;
    }
}

// ---------------------------------------------------------------------------
// Kernel: abstraction loss (1 block, 64 threads = 1 wave)
__global__ __launch_bounds__(64) void k_loss(const float* __restrict__ out,
                                             const int* __restrict__ positions,
                                             const int* __restrict__ tts,
                                             float* __restrict__ loss_out) {
    int b = threadIdx.x;
    int pos = positions[b];
    int tt = tts[b];
    size_t base = ((size_t)(b * LL + pos)) * 553 + 512;
    float mx = -3.4e38f;
    float lp_t = 0.0f;
    float lps[41];
    for (int i = 0; i < 41; ++i) {
        float p = out[base + i];
        p = fminf(fmaxf(p, 1e-10f), 1.0f);
        float lp = __logf(p);
        lps[i] = lp;
        mx = fmaxf(mx, lp);
        if (i == tt) lp_t = lp;
    }
    float s = 0.0f;
    for (int i = 0; i < 41; ++i) s += __expf(lps[i] - mx);
    float lse = mx + __logf(s);
    float val = lp_t - lse;
    float a = -val / 64.0f;
    for (int off = 32; off; off >>= 1) a += __shfl_xor(a, off, 64);
    if (b == 0) *loss_out = a;
}

// ---------------------------------------------------------------------------
// Kernel: template application (new_d) + dt broadcast write
// grid 16384 x 256
__global__ __launch_bounds__(256) void k_newd(const float* __restrict__ dl,
                                              const float* __restrict__ dr,
                                              const int* __restrict__ codes,
                                              const float* __restrict__ dtf,
                                              float* __restrict__ newd,
                                              float* __restrict__ dtout) {
    int row = blockIdx.x;
    int t = threadIdx.x;
    int b = row >> 8;
    __shared__ int sT[32];
    __shared__ int sO[32];
    __shared__ int lens[2];
    __shared__ int cds[8];

    if (t < 2) lens[t] = 0;
    if (t < 32) sT[t] = 0;
    if (t < 8) cds[t] = codes[b * 8 + t];
    __syncthreads();
    size_t dbase = (size_t)row * (MM * VV);
    if (t < 32) {
        if (dl[dbase + (size_t)t * VV] < 0.5f) atomicAdd(&lens[0], 1);
        if (dr[dbase + (size_t)t * VV] < 0.5f) atomicAdd(&lens[1], 1);
    }
    __syncthreads();
    if (t == 0) {
        int idx = 0;
        bool done = false;
        int ll = lens[0], lr = lens[1];
        for (int k = 0; k < 8; ++k) {
            int code = cds[k];
            if (done) continue;
            if (code == 0) {
                if (ll > 0 && idx + ll <= MM) {
                    for (int m = 0; m < ll; ++m) { sT[idx + m] = 1; sO[idx + m] = m; }
                    idx += ll;
                }
            } else if (code == 1) {
                if (lr > 0 && idx + lr <= MM) {
                    for (int m = 0; m < lr; ++m) { sT[idx + m] = 2; sO[idx + m] = m; }
                    idx += lr;
                }
            } else {
                if (idx < MM) { sT[idx] = 3; done = true; }
            }
        }
    }
    __syncthreads();
#pragma unroll
    for (int rep = 0; rep < 2; ++rep) {
        int e4 = t + rep * 256;        // float4 index within (32x64)
        int m = e4 >> 4, v4 = e4 & 15;
        int st = sT[m];
        float4 val = {0.0f, 0.0f, 0.0f, 0.0f};
        if (st == 1) val = *(const float4*)(dl + dbase + (size_t)sO[m] * VV + v4 * 4);
        else if (st == 2) val = *(const float4*)(dr + dbase + (size_t)sO[m] * VV + v4 * 4);
        else if (st == 3 && v4 == 0) val.x = 1.0f;
        *(float4*)(newd + dbase + (size_t)e4 * 4) = val;
    }
    if (t < 24) dtout[(size_t)row * 24 + t] = dtf[b * 24 + t];
}

// ---------------------------------------------------------------------------
extern "C" void kernel_launch(void* const* d_in, const int* in_sizes, int n_in,
                              void* d_out, int out_size, void* d_ws, size_t ws_size,
                              hipStream_t stream) {
    const float* hl = (const float*)d_in[0];
    const float* hr = (const float*)d_in[1];
    const float* cl = (const float*)d_in[2];
    const float* cr = (const float*)d_in[3];
    const float* dl = (const float*)d_in[4];
    const float* dr = (const float*)d_in[5];
    const int* target_types = (const int*)d_in[6];
    const int* positions = (const int*)d_in[7];
    const float* comp_W = (const float*)d_in[8];
    const float* comp_b = (const float*)d_in[9];
    const float* tp_W1 = (const float*)d_in[10];
    const float* tp_b1 = (const float*)d_in[11];
    const float* tp_W2 = (const float*)d_in[12];
    const float* tp_b2 = (const float*)d_in[13];
    const float* tp_W3 = (const float*)d_in[14];
    const float* tp_b3 = (const float*)d_in[15];
    const float* dec_W = (const float*)d_in[16];
    const float* dec_b = (const float*)d_in[17];
    const float* type_emb = (const float*)d_in[18];
    const float* gumbel = (const float*)d_in[19];

    float* out = (float*)d_out;

    // workspace layout: hlr bf16 (padded) | codes | dtf
    const size_t HLR_BYTES = (size_t)BB * LL * D2P * 2;   // 36,700,160
    unsigned short* hlr = (unsigned short*)d_ws;
    int* codes = (int*)((char*)d_ws + HLR_BYTES);
    float* dtf = (float*)((char*)d_ws + HLR_BYTES + 2048);

    // v (bf16) staged inside d_out's new_d region (overwritten later by k_newd)
    unsigned short* vws = (unsigned short*)(out + OFF_NEWD);

    k_hlr<<<BB * LL, 256, 0, stream>>>(hl, hr, hlr);
    k_dec<<<BB, 64, 0, stream>>>(type_emb, dec_W, dec_b, target_types, codes, dtf);
    k_gemm<<<dim3(FIVE_DV / 128, LL / 128, BB), 256, 0, stream>>>(
        hlr, comp_W, comp_b, target_types, vws);
    k_cell<<<BB * LL, 256, 0, stream>>>(vws, cl, cr, tp_W1, tp_b1, tp_W2, tp_b2,
                                        tp_W3, tp_b3, gumbel, out);
    k_loss<<<1, 64, 0, stream>>>(out, positions, target_types, out + OFF_LOSS);
    k_newd<<<BB * LL, 256, 0, stream>>>(dl, dr, codes, dtf, out + OFF_NEWD,
                                        out + OFF_DT);
}